// Round 8
// baseline (143.006 us; speedup 1.0000x reference)
//
#include <hip/hip_runtime.h>
#include <hip/hip_cooperative_groups.h>
#include <hip/hip_bf16.h>
#include <math.h>

namespace cg = cooperative_groups;

typedef short bf4 __attribute__((ext_vector_type(4)));
typedef float f32x4 __attribute__((ext_vector_type(4)));

constexpr int CC  = 128;
constexpr int NH  = 8;
constexpr int KD  = 16;
constexpr int BB  = 8;
constexpr int NN  = 1024;
constexpr int BHW = BB * NN;
constexpr float LOG2E = 1.44269504088896340736f;

static __device__ __forceinline__ short f2bf(float x) {
    __hip_bfloat16 b = __float2bfloat16(x);
    short s;
    __builtin_memcpy(&s, &b, 2);
    return s;
}
static __device__ __forceinline__ float bf2f(short s) {
    unsigned u = ((unsigned)(unsigned short)s) << 16;
    float f;
    __builtin_memcpy(&f, &u, 4);
    return f;
}
static __device__ __forceinline__ unsigned fbits(float x) {
    unsigned u;
    __builtin_memcpy(&u, &x, 4);
    return u;
}

static __device__ __forceinline__ f32x4 mfma16(bf4 a, bf4 b, f32x4 c) {
#if __has_builtin(__builtin_amdgcn_mfma_f32_16x16x16bf16_1k)
    return __builtin_amdgcn_mfma_f32_16x16x16bf16_1k(a, b, c, 0, 0, 0);
#else
    f32x4 d;
    asm volatile("v_mfma_f32_16x16x16_bf16 %0, %1, %2, %3"
                 : "=&v"(d) : "v"(a), "v"(b), "v"(c));
    return d;
#endif
}

// ================= fused cooperative kernel: 512 blocks x 512 =================
// 2 blocks/CU needed (LDS 33.3KB -> 4 possible; VGPR capped 128 -> 2). Phases:
// A: BN partial sums, block=(c, quarter); blocks 0-23 also W->bf16 frags.
// B: proj block=(it,b): finish stats from ps (L2), BN+GELU->B-frags, MFMA.
// C: attn block=(bh, yg): stage K head once, 8 waves = 8 i-tiles.
__global__ __launch_bounds__(512, 4) void k_fused(
        const float* __restrict__ x,
        const float* __restrict__ gamma,
        const float* __restrict__ beta,
        const float* __restrict__ wq,
        const float* __restrict__ wk,
        const float* __restrict__ wv,
        const float* __restrict__ peh,
        const float* __restrict__ pew,
        float* __restrict__ out,
        float* __restrict__ ps,   // [128][4][2] partial sums
        short* __restrict__ wf,
        short* __restrict__ qf,
        short* __restrict__ kf,
        short* __restrict__ vf) {
    __shared__ union {
        struct { short ldsK[16384]; float phS[64], pwS[64], redS[8]; } a;
        struct { float xS[128][20]; float ssS[256]; short afS[8][256]; } p;
        struct { float r1[8], r2[8]; } s;
    } sm;

    int blk = blockIdx.x;
    int t = threadIdx.x;
    int wid = t >> 6, lane = t & 63;
    int hl = lane >> 4, li = lane & 15;

    // ---------------- phase A: BN partial sums + W conversion ----------------
    {
        int c = blk >> 2, part = blk & 3;
        int b = 2 * part + (t >> 8);
        int off = t & 255;
        float4 v = ((const float4*)(x + ((size_t)b * CC + c) * NN))[off];
        float s1 = v.x + v.y + v.z + v.w;
        float s2 = v.x * v.x + v.y * v.y + v.z * v.z + v.w * v.w;
        #pragma unroll
        for (int o = 32; o >= 1; o >>= 1) {
            s1 += __shfl_xor(s1, o);
            s2 += __shfl_xor(s2, o);
        }
        if (lane == 0) { sm.s.r1[wid] = s1; sm.s.r2[wid] = s2; }
        __syncthreads();
        if (t == 0) {
            float a1 = 0.f, a2 = 0.f;
            #pragma unroll
            for (int w = 0; w < 8; ++w) { a1 += sm.s.r1[w]; a2 += sm.s.r2[w]; }
            ps[c * 8 + part * 2 + 0] = a1;
            ps[c * 8 + part * 2 + 1] = a2;
        }
        if (blk < 24) {
            // Wf[((p*8+mt)*8+ct)*64 + ln][jj] = W_p[mt*16+li][ct*16+4*hl+jj]
            int s = blk * 512 + t;   // 0..12287
            int ln = s & 63, ct = (s >> 6) & 7, mt = (s >> 9) & 7, p = s >> 12;
            int hl_ = ln >> 4, li_ = ln & 15;
            const float* w = (p == 0) ? wq : (p == 1) ? wk : wv;
            float4 v4 = *(const float4*)(w + (size_t)(mt * 16 + li_) * CC + ct * 16 + 4 * hl_);
            float sc = (p == 0) ? 0.25f * LOG2E : 1.0f;
            bf4 r;
            r[0] = f2bf(v4.x * sc); r[1] = f2bf(v4.y * sc);
            r[2] = f2bf(v4.z * sc); r[3] = f2bf(v4.w * sc);
            *(bf4*)&wf[(size_t)s * 4] = r;
        }
    }
    cg::this_grid().sync();

    // ---------------- phase B: projection ----------------
    {
        int it = blk & 63, b = blk >> 6;
        if (t < 128) {
            int c = t;
            const float4* pp = (const float4*)(ps + c * 8);
            float4 a0 = pp[0], a1 = pp[1];
            float s1 = a0.x + a0.z + a1.x + a1.z;
            float s2 = a0.y + a0.w + a1.y + a1.w;
            float mean = s1 / (float)BHW;
            float var  = s2 / (float)BHW - mean * mean;
            float rstd = rsqrtf(var + 1e-5f);
            float sc = rstd * gamma[c];
            sm.p.ssS[c]       = sc;
            sm.p.ssS[128 + c] = beta[c] - mean * sc;
        }
        const float* xb = x + (size_t)b * CC * NN + it * 16;
        {
            int r = t >> 2, cf = t & 3;
            float4 v = *(const float4*)(xb + (size_t)r * NN + cf * 4);
            *(float4*)&sm.p.xS[r][cf * 4] = v;
        }
        __syncthreads();
        {
            int ct = t >> 6, ln = t & 63;
            int hl_ = ln >> 4, li_ = ln & 15;
            int c0 = ct * 16 + 4 * hl_;
            bf4 r;
            #pragma unroll
            for (int jj = 0; jj < 4; ++jj) {
                int c = c0 + jj;
                float v = sm.p.xS[c][li_] * sm.p.ssS[c] + sm.p.ssS[128 + c];
                v = 0.5f * v * (1.0f + erff(v * 0.70710678f));
                r[jj] = f2bf(v);
            }
            *(bf4*)&sm.p.afS[ct][ln * 4] = r;
        }
        __syncthreads();

        f32x4 acc[3];
        #pragma unroll
        for (int e = 0; e < 3; ++e) acc[e] = (f32x4)0.f;
        #pragma unroll
        for (int ct = 0; ct < 8; ++ct) {
            bf4 af = *(const bf4*)&sm.p.afS[ct][lane * 4];
            #pragma unroll
            for (int e = 0; e < 3; ++e) {
                int mtp = wid * 3 + e, p = mtp >> 3, mt = mtp & 7;
                bf4 wfr = *(const bf4*)(wf + ((size_t)((p * 8 + mt) * 8 + ct) * 64 + lane) * 4);
                acc[e] = mfma16(wfr, af, acc[e]);
            }
        }

        int bq = b * 8;
        #pragma unroll
        for (int e = 0; e < 3; ++e) {
            int mtp = wid * 3 + e, p = mtp >> 3, h = mtp & 7;
            if (p < 2) {
                short* dst = (p == 0) ? qf : kf;
                bf4 r;
                #pragma unroll
                for (int jr = 0; jr < 4; ++jr) r[jr] = f2bf(acc[e][jr]);
                *(bf4*)&dst[(((size_t)(bq + h) * 64 + it) * 64 + lane) * 4] = r;
            }
        }
        float* vScr = &sm.p.xS[0][0];   // [8][16][17] f32
        __syncthreads();
        #pragma unroll
        for (int e = 0; e < 3; ++e) {
            int mtp = wid * 3 + e;
            if (mtp >= 16) {
                int h = mtp & 7;
                #pragma unroll
                for (int r = 0; r < 4; ++r)
                    vScr[(h * 16 + 4 * hl + r) * 17 + li] = acc[e][r];
            }
        }
        __syncthreads();
        {
            int hh = wid;
            bf4 r;
            #pragma unroll
            for (int jj = 0; jj < 4; ++jj)
                r[jj] = f2bf(vScr[(hh * 16 + li) * 17 + 4 * hl + jj]);
            *(bf4*)&vf[(((size_t)(bq + hh) * 64 + it) * 64 + lane) * 4] = r;
        }
    }
    cg::this_grid().sync();

    // ---------------- phase C: attention ----------------
    {
        int bh = blk & 63;
        int yg = blk >> 6;                 // 0..7
        const short* qfh = qf + (size_t)bh * 16384;
        const short* kfh = kf + (size_t)bh * 16384;
        const short* vfh = vf + (size_t)bh * 16384;

        #pragma unroll
        for (int k = 0; k < 4; ++k)
            ((int4*)sm.a.ldsK)[t + 512 * k] = ((const int4*)kfh)[t + 512 * k];
        if (t < 64) {
            sm.a.phS[t] = (t < 63) ? peh[t] * LOG2E : -1e30f;
            sm.a.pwS[t] = (t < 63) ? pew[t] * LOG2E : -1e30f;
        }
        __syncthreads();

        int it = yg * 8 + wid;

        // kmax scan from LDS: wave covers 8 j-tiles
        float knm = 0.f;
        #pragma unroll 4
        for (int jt2 = wid * 8; jt2 < wid * 8 + 8; ++jt2) {
            bf4 kb = *(const bf4*)&sm.a.ldsK[jt2 * 256 + lane * 4];
            float s = 0.f;
            #pragma unroll
            for (int jj = 0; jj < 4; ++jj) {
                float kv = bf2f(kb[jj]);
                s = fmaf(kv, kv, s);
            }
            s += __shfl_xor(s, 16);
            s += __shfl_xor(s, 32);
            knm = fmaxf(knm, s);
        }
        knm = fmaxf(knm, __shfl_xor(knm, 1));
        knm = fmaxf(knm, __shfl_xor(knm, 2));
        knm = fmaxf(knm, __shfl_xor(knm, 4));
        knm = fmaxf(knm, __shfl_xor(knm, 8));
        if (lane == 0) sm.a.redS[wid] = knm;
        __syncthreads();
        float kmax = sm.a.redS[0];
        #pragma unroll
        for (int w = 1; w < 8; ++w) kmax = fmaxf(kmax, sm.a.redS[w]);
        kmax = sqrtf(kmax);

        float mph = sm.a.phS[lane], mpw = sm.a.pwS[lane];
        #pragma unroll
        for (int o = 32; o >= 1; o >>= 1) {
            mph = fmaxf(mph, __shfl_xor(mph, o));
            mpw = fmaxf(mpw, __shfl_xor(mpw, o));
        }
        float biasmax = mph + mpw;

        bf4 qfr = *(const bf4*)(qfh + ((size_t)it * 64 + lane) * 4);
        float qn2 = 0.f;
        #pragma unroll
        for (int jj = 0; jj < 4; ++jj) {
            float qv = bf2f(qfr[jj]);
            qn2 = fmaf(qv, qv, qn2);
        }
        qn2 += __shfl_xor(qn2, 16);
        qn2 += __shfl_xor(qn2, 32);
        float Mi = sqrtf(qn2) * kmax + biasmax;

        int wi = ((it & 1) << 4) | li;
        float pwm[2][4];
        #pragma unroll
        for (int jp = 0; jp < 2; ++jp)
            #pragma unroll
            for (int r = 0; r < 4; ++r)
                pwm[jp][r] = sm.a.pwS[wi + 31 - ((jp << 4) + 4 * hl + r)] - Mi;

        int hq = it >> 1;
        f32x4 oacc = (f32x4)0.f;
        float lsum = 0.f;

        bf4 vA[4], vB[4];
        auto loadV = [&](bf4* vb, int ch) {
            const short* vp = vfh + ((size_t)ch * 4 * 64 + lane) * 4;
            #pragma unroll
            for (int jt = 0; jt < 4; ++jt)
                vb[jt] = *(const bf4*)(vp + jt * 256);
        };
        auto compute = [&](bf4* vb, int ch) {
            float ph0 = sm.a.phS[hq + 31 - 2 * ch];
            float ph1 = sm.a.phS[hq + 30 - 2 * ch];
            f32x4 s[4];
            #pragma unroll
            for (int jt = 0; jt < 4; ++jt) {
                bf4 kb = *(const bf4*)&sm.a.ldsK[(ch * 4 + jt) * 256 + lane * 4];
                float ph = (jt < 2) ? ph0 : ph1;
                f32x4 c;
                #pragma unroll
                for (int r = 0; r < 4; ++r) c[r] = pwm[jt & 1][r] + ph;
                s[jt] = mfma16(kb, qfr, c);
            }
            #pragma unroll
            for (int jt = 0; jt < 4; ++jt) {
                #pragma unroll
                for (int r = 0; r < 4; ++r) {
                    s[jt][r] = exp2f(s[jt][r]);
                    lsum += s[jt][r];
                }
            }
            #pragma unroll
            for (int jt = 0; jt < 4; ++jt) {
                unsigned lo = __builtin_amdgcn_perm(fbits(s[jt][1]), fbits(s[jt][0]), 0x07060302u);
                unsigned hi = __builtin_amdgcn_perm(fbits(s[jt][3]), fbits(s[jt][2]), 0x07060302u);
                unsigned pk[2] = {lo, hi};
                bf4 pf;
                __builtin_memcpy(&pf, pk, 8);
                oacc = mfma16(vb[jt], pf, oacc);
            }
        };

        loadV(vA, 0);
        #pragma unroll 1
        for (int ch = 0; ch < 16; ch += 2) {
            loadV(vB, ch + 1);
            compute(vA, ch);
            if (ch + 2 < 16) loadV(vA, ch + 2);
            compute(vB, ch + 1);
        }

        lsum += __shfl_xor(lsum, 16);
        lsum += __shfl_xor(lsum, 32);
        float rl = 1.0f / lsum;

        int b = bh >> 3, h = bh & 7;
        size_t base = (size_t)b * (CC * NN) + (size_t)h * KD * NN;
        int i = it * 16 + li;
        #pragma unroll
        for (int r = 0; r < 4; ++r) {
            int d = 4 * hl + r;
            size_t g = base + (size_t)d * NN + i;
            out[g] = x[g] + oacc[r] * rl;
        }
    }
}

// ================= fallback path: round-6 three-kernel pipeline =================
__global__ __launch_bounds__(256) void k_prep(const float* __restrict__ x,
                                              const float* __restrict__ gamma,
                                              const float* __restrict__ beta,
                                              const float* __restrict__ wq,
                                              const float* __restrict__ wk,
                                              const float* __restrict__ wv,
                                              float* __restrict__ ss,
                                              short* __restrict__ wf) {
    int t = threadIdx.x;
    if (blockIdx.x < 128) {
        int c = blockIdx.x;
        float s1 = 0.f, s2 = 0.f;
        #pragma unroll
        for (int k = 0; k < 8; ++k) {
            int e = t + 256 * k;
            int b = e >> 8, off = e & 255;
            float4 v = ((const float4*)(x + ((size_t)b * CC + c) * NN))[off];
            s1 += v.x + v.y + v.z + v.w;
            s2 += v.x * v.x + v.y * v.y + v.z * v.z + v.w * v.w;
        }
        #pragma unroll
        for (int off = 32; off >= 1; off >>= 1) {
            s1 += __shfl_xor(s1, off);
            s2 += __shfl_xor(s2, off);
        }
        __shared__ float r1[4], r2[4];
        int wid = t >> 6, lane = t & 63;
        if (lane == 0) { r1[wid] = s1; r2[wid] = s2; }
        __syncthreads();
        if (t == 0) {
            float a1 = r1[0] + r1[1] + r1[2] + r1[3];
            float a2 = r2[0] + r2[1] + r2[2] + r2[3];
            float mean = a1 / (float)BHW;
            float var  = a2 / (float)BHW - mean * mean;
            float rstd = rsqrtf(var + 1e-5f);
            float sc = rstd * gamma[c];
            ss[c]      = sc;
            ss[CC + c] = beta[c] - mean * sc;
        }
    } else {
        int s = (blockIdx.x - 128) * 256 + t;
        int lane = s & 63, ct = (s >> 6) & 7, mt = (s >> 9) & 7, p = s >> 12;
        int hl = lane >> 4, li = lane & 15;
        const float* w = (p == 0) ? wq : (p == 1) ? wk : wv;
        float4 v = *(const float4*)(w + (size_t)(mt * 16 + li) * CC + ct * 16 + 4 * hl);
        float sc = (p == 0) ? 0.25f * LOG2E : 1.0f;
        bf4 r;
        r[0] = f2bf(v.x * sc); r[1] = f2bf(v.y * sc);
        r[2] = f2bf(v.z * sc); r[3] = f2bf(v.w * sc);
        *(bf4*)&wf[(size_t)s * 4] = r;
    }
}

__global__ __launch_bounds__(512) void k_proj(const float* __restrict__ x,
                                              const float* __restrict__ ss,
                                              const short* __restrict__ wf,
                                              short* __restrict__ qf,
                                              short* __restrict__ kf,
                                              short* __restrict__ vf) {
    __shared__ float xS[128][20];
    __shared__ float ssS[256];
    __shared__ short afS[8][256];
    int it = blockIdx.x, b = blockIdx.y;
    int t = threadIdx.x;
    if (t < 256) ssS[t] = ss[t];
    const float* xb = x + (size_t)b * CC * NN + it * 16;
    {
        int r = t >> 2, cf = t & 3;
        float4 v = *(const float4*)(xb + (size_t)r * NN + cf * 4);
        *(float4*)&xS[r][cf * 4] = v;
    }
    __syncthreads();
    {
        int ct = t >> 6, ln = t & 63;
        int hl_ = ln >> 4, li_ = ln & 15;
        int c0 = ct * 16 + 4 * hl_;
        bf4 r;
        #pragma unroll
        for (int jj = 0; jj < 4; ++jj) {
            int c = c0 + jj;
            float v = xS[c][li_] * ssS[c] + ssS[128 + c];
            v = 0.5f * v * (1.0f + erff(v * 0.70710678f));
            r[jj] = f2bf(v);
        }
        *(bf4*)&afS[ct][ln * 4] = r;
    }
    __syncthreads();

    int wid = t >> 6, lane = t & 63;
    int hl = lane >> 4, li = lane & 15;
    f32x4 acc[3];
    #pragma unroll
    for (int e = 0; e < 3; ++e) acc[e] = (f32x4)0.f;
    #pragma unroll
    for (int ct = 0; ct < 8; ++ct) {
        bf4 af = *(const bf4*)&afS[ct][lane * 4];
        #pragma unroll
        for (int e = 0; e < 3; ++e) {
            int mtp = wid * 3 + e, p = mtp >> 3, mt = mtp & 7;
            bf4 wfr = *(const bf4*)(wf + ((size_t)((p * 8 + mt) * 8 + ct) * 64 + lane) * 4);
            acc[e] = mfma16(wfr, af, acc[e]);
        }
    }
    int bq = b * 8;
    #pragma unroll
    for (int e = 0; e < 3; ++e) {
        int mtp = wid * 3 + e, p = mtp >> 3, h = mtp & 7;
        if (p < 2) {
            short* dst = (p == 0) ? qf : kf;
            bf4 r;
            #pragma unroll
            for (int jr = 0; jr < 4; ++jr) r[jr] = f2bf(acc[e][jr]);
            *(bf4*)&dst[(((size_t)(bq + h) * 64 + it) * 64 + lane) * 4] = r;
        }
    }
    float* vScr = &xS[0][0];
    __syncthreads();
    #pragma unroll
    for (int e = 0; e < 3; ++e) {
        int mtp = wid * 3 + e;
        if (mtp >= 16) {
            int h = mtp & 7;
            #pragma unroll
            for (int r = 0; r < 4; ++r)
                vScr[(h * 16 + 4 * hl + r) * 17 + li] = acc[e][r];
        }
    }
    __syncthreads();
    {
        int hh = wid;
        bf4 r;
        #pragma unroll
        for (int jj = 0; jj < 4; ++jj)
            r[jj] = f2bf(vScr[(hh * 16 + li) * 17 + 4 * hl + jj]);
        *(bf4*)&vf[(((size_t)(bq + hh) * 64 + it) * 64 + lane) * 4] = r;
    }
}

__global__ __launch_bounds__(256, 4) void k_attn(const short* __restrict__ qf,
                                                 const short* __restrict__ kf,
                                                 const short* __restrict__ vf,
                                                 const float* __restrict__ x,
                                                 const float* __restrict__ peh,
                                                 const float* __restrict__ pew,
                                                 float* __restrict__ out) {
    __shared__ short ldsK[16384];
    __shared__ float phS[64], pwS[64], redS[4];
    int t = threadIdx.x;
    int bh = blockIdx.x;
    const short* qfh = qf + (size_t)bh * 16384;
    const short* kfh = kf + (size_t)bh * 16384;
    const short* vfh = vf + (size_t)bh * 16384;

    #pragma unroll
    for (int k = 0; k < 8; ++k)
        ((int4*)ldsK)[t + 256 * k] = ((const int4*)kfh)[t + 256 * k];
    if (t < 64) {
        phS[t] = (t < 63) ? peh[t] * LOG2E : -1e30f;
        pwS[t] = (t < 63) ? pew[t] * LOG2E : -1e30f;
    }
    __syncthreads();

    int wid = t >> 6, lane = t & 63;
    int li = lane & 15, hl = lane >> 4;
    int it = blockIdx.y * 4 + wid;

    float knm = 0.f;
    #pragma unroll 4
    for (int jt2 = wid * 16; jt2 < wid * 16 + 16; ++jt2) {
        bf4 kb = *(const bf4*)&ldsK[jt2 * 256 + lane * 4];
        float s = 0.f;
        #pragma unroll
        for (int jj = 0; jj < 4; ++jj) {
            float kv = bf2f(kb[jj]);
            s = fmaf(kv, kv, s);
        }
        s += __shfl_xor(s, 16);
        s += __shfl_xor(s, 32);
        knm = fmaxf(knm, s);
    }
    knm = fmaxf(knm, __shfl_xor(knm, 1));
    knm = fmaxf(knm, __shfl_xor(knm, 2));
    knm = fmaxf(knm, __shfl_xor(knm, 4));
    knm = fmaxf(knm, __shfl_xor(knm, 8));
    if (lane == 0) redS[wid] = knm;
    __syncthreads();
    float kmax = sqrtf(fmaxf(fmaxf(redS[0], redS[1]), fmaxf(redS[2], redS[3])));

    float mph = phS[lane], mpw = pwS[lane];
    #pragma unroll
    for (int off = 32; off >= 1; off >>= 1) {
        mph = fmaxf(mph, __shfl_xor(mph, off));
        mpw = fmaxf(mpw, __shfl_xor(mpw, off));
    }
    float biasmax = mph + mpw;

    bf4 qfr = *(const bf4*)(qfh + ((size_t)it * 64 + lane) * 4);
    float qn2 = 0.f;
    #pragma unroll
    for (int jj = 0; jj < 4; ++jj) {
        float qv = bf2f(qfr[jj]);
        qn2 = fmaf(qv, qv, qn2);
    }
    qn2 += __shfl_xor(qn2, 16);
    qn2 += __shfl_xor(qn2, 32);
    float Mi = sqrtf(qn2) * kmax + biasmax;

    int wi = ((it & 1) << 4) | li;
    float pwm[2][4];
    #pragma unroll
    for (int jp = 0; jp < 2; ++jp)
        #pragma unroll
        for (int r = 0; r < 4; ++r)
            pwm[jp][r] = pwS[wi + 31 - ((jp << 4) + 4 * hl + r)] - Mi;

    int hq = it >> 1;
    f32x4 oacc = (f32x4)0.f;
    float lsum = 0.f;

    bf4 vA[4], vB[4];
    auto loadV = [&](bf4* vb, int ch) {
        const short* vp = vfh + ((size_t)ch * 4 * 64 + lane) * 4;
        #pragma unroll
        for (int jt = 0; jt < 4; ++jt)
            vb[jt] = *(const bf4*)(vp + jt * 256);
    };
    auto compute = [&](bf4* vb, int ch) {
        float ph0 = phS[hq + 31 - 2 * ch];
        float ph1 = phS[hq + 30 - 2 * ch];
        f32x4 s[4];
        #pragma unroll
        for (int jt = 0; jt < 4; ++jt) {
            bf4 kb = *(const bf4*)&ldsK[(ch * 4 + jt) * 256 + lane * 4];
            float ph = (jt < 2) ? ph0 : ph1;
            f32x4 c;
            #pragma unroll
            for (int r = 0; r < 4; ++r) c[r] = pwm[jt & 1][r] + ph;
            s[jt] = mfma16(kb, qfr, c);
        }
        #pragma unroll
        for (int jt = 0; jt < 4; ++jt) {
            #pragma unroll
            for (int r = 0; r < 4; ++r) {
                s[jt][r] = exp2f(s[jt][r]);
                lsum += s[jt][r];
            }
        }
        #pragma unroll
        for (int jt = 0; jt < 4; ++jt) {
            unsigned lo = __builtin_amdgcn_perm(fbits(s[jt][1]), fbits(s[jt][0]), 0x07060302u);
            unsigned hi = __builtin_amdgcn_perm(fbits(s[jt][3]), fbits(s[jt][2]), 0x07060302u);
            unsigned pk[2] = {lo, hi};
            bf4 pf;
            __builtin_memcpy(&pf, pk, 8);
            oacc = mfma16(vb[jt], pf, oacc);
        }
    };

    loadV(vA, 0);
    #pragma unroll 1
    for (int ch = 0; ch < 16; ch += 2) {
        loadV(vB, ch + 1);
        compute(vA, ch);
        if (ch + 2 < 16) loadV(vA, ch + 2);
        compute(vB, ch + 1);
    }

    lsum += __shfl_xor(lsum, 16);
    lsum += __shfl_xor(lsum, 32);
    float rl = 1.0f / lsum;

    int b = bh >> 3, h = bh & 7;
    size_t base = (size_t)b * (CC * NN) + (size_t)h * KD * NN;
    int i = it * 16 + li;
    #pragma unroll
    for (int r = 0; r < 4; ++r) {
        int d = 4 * hl + r;
        size_t g = base + (size_t)d * NN + i;
        out[g] = x[g] + oacc[r] * rl;
    }
}

extern "C" void kernel_launch(void* const* d_in, const int* in_sizes, int n_in,
                              void* d_out, int out_size, void* d_ws, size_t ws_size,
                              hipStream_t stream) {
    const float* x     = (const float*)d_in[0];
    const float* gamma = (const float*)d_in[1];
    const float* beta  = (const float*)d_in[2];
    const float* wq    = (const float*)d_in[3];
    const float* wk    = (const float*)d_in[4];
    const float* wv    = (const float*)d_in[5];
    const float* peh   = (const float*)d_in[6];
    const float* pew   = (const float*)d_in[7];
    float* out = (float*)d_out;
    float* ws  = (float*)d_ws;

    float* ps = ws;                          // 1024 f32 partial sums
    float* ss = ws + 1024;                   // 256 f32 (fallback path)
    short* wf = (short*)(ws + 1280);         // 49152 shorts: W bf16 frags
    short* qf = wf + 49152;                  // 1M shorts each (2 MB)
    short* kf = qf + (1 << 20);
    short* vf = kf + (1 << 20);

    void* args[] = {(void*)&x, (void*)&gamma, (void*)&beta, (void*)&wq, (void*)&wk,
                    (void*)&wv, (void*)&peh, (void*)&pew, (void*)&out, (void*)&ps,
                    (void*)&wf, (void*)&qf, (void*)&kf, (void*)&vf};
    hipError_t err = hipLaunchCooperativeKernel((const void*)k_fused, dim3(512),
                                                dim3(512), args, 0, stream);
    if (err != hipSuccess) {
        (void)hipGetLastError();   // clear sticky error
        k_prep<<<176, 256, 0, stream>>>(x, gamma, beta, wq, wk, wv, ss, wf);
        k_proj<<<dim3(64, 8), 512, 0, stream>>>(x, ss, wf, qf, kf, vf);
        k_attn<<<dim3(64, 16), 256, 0, stream>>>(qf, kf, vf, x, peh, pew, out);
    }
}

// Round 9
// 66.766 us; speedup vs baseline: 2.1419x; 2.1419x over previous
//
#include <hip/hip_runtime.h>
#include <hip/hip_bf16.h>
#include <math.h>

typedef short bf4 __attribute__((ext_vector_type(4)));
typedef float f32x4 __attribute__((ext_vector_type(4)));

constexpr int CC  = 128;
constexpr int NH  = 8;
constexpr int KD  = 16;
constexpr int BB  = 8;
constexpr int NN  = 1024;
constexpr int BHW = BB * NN;
constexpr float LOG2E = 1.44269504088896340736f;

static __device__ __forceinline__ short f2bf(float x) {
    __hip_bfloat16 b = __float2bfloat16(x);
    short s;
    __builtin_memcpy(&s, &b, 2);
    return s;
}
static __device__ __forceinline__ float bf2f(short s) {
    unsigned u = ((unsigned)(unsigned short)s) << 16;
    float f;
    __builtin_memcpy(&f, &u, 4);
    return f;
}
static __device__ __forceinline__ unsigned fbits(float x) {
    unsigned u;
    __builtin_memcpy(&u, &x, 4);
    return u;
}

static __device__ __forceinline__ f32x4 mfma16(bf4 a, bf4 b, f32x4 c) {
#if __has_builtin(__builtin_amdgcn_mfma_f32_16x16x16bf16_1k)
    return __builtin_amdgcn_mfma_f32_16x16x16bf16_1k(a, b, c, 0, 0, 0);
#else
    f32x4 d;
    asm volatile("v_mfma_f32_16x16x16_bf16 %0, %1, %2, %3"
                 : "=&v"(d) : "v"(a), "v"(b), "v"(c));
    return d;
#endif
}

// ---------------- K1: BN partial stats (2-way split) + W->bf16 frags ----
// blocks 0..255: (c, half) -> ps[c*4 + half*2 + {0,1}] partial s1/s2.
// blocks 256..303: wq/wk/wv -> bf16 A-fragments (q pre-scaled).
__global__ __launch_bounds__(256) void k_prep(const float* __restrict__ x,
                                              const float* __restrict__ wq,
                                              const float* __restrict__ wk,
                                              const float* __restrict__ wv,
                                              float* __restrict__ ps,
                                              short* __restrict__ wf) {
    int t = threadIdx.x;
    int blk = blockIdx.x;
    if (blk < 256) {
        int c = blk >> 1, half = blk & 1;
        float s1 = 0.f, s2 = 0.f;
        #pragma unroll
        for (int k = 0; k < 4; ++k) {
            int b = half * 4 + k;
            float4 v = ((const float4*)(x + ((size_t)b * CC + c) * NN))[t];
            s1 += v.x + v.y + v.z + v.w;
            s2 += v.x * v.x + v.y * v.y + v.z * v.z + v.w * v.w;
        }
        #pragma unroll
        for (int off = 32; off >= 1; off >>= 1) {
            s1 += __shfl_xor(s1, off);
            s2 += __shfl_xor(s2, off);
        }
        __shared__ float r1[4], r2[4];
        int wid = t >> 6, lane = t & 63;
        if (lane == 0) { r1[wid] = s1; r2[wid] = s2; }
        __syncthreads();
        if (t == 0) {
            ps[c * 4 + half * 2 + 0] = r1[0] + r1[1] + r1[2] + r1[3];
            ps[c * 4 + half * 2 + 1] = r2[0] + r2[1] + r2[2] + r2[3];
        }
    } else {
        // Wf[((p*8+mt)*8+ct)*64 + ln][jj] = W_p[mt*16+li][ct*16+4*hl+jj]
        int s = (blk - 256) * 256 + t;   // 0..12287
        int ln = s & 63, ct = (s >> 6) & 7, mt = (s >> 9) & 7, p = s >> 12;
        int hl = ln >> 4, li = ln & 15;
        const float* w = (p == 0) ? wq : (p == 1) ? wk : wv;
        float4 v = *(const float4*)(w + (size_t)(mt * 16 + li) * CC + ct * 16 + 4 * hl);
        float sc = (p == 0) ? 0.25f * LOG2E : 1.0f;
        bf4 r;
        r[0] = f2bf(v.x * sc); r[1] = f2bf(v.y * sc);
        r[2] = f2bf(v.z * sc); r[3] = f2bf(v.w * sc);
        *(bf4*)&wf[(size_t)s * 4] = r;
    }
}

// ---------------- K2: fused BN+GELU + QKV projection via MFMA -----------
// grid (64, 8): x = 16-pixel tile, y = batch. block 512 (8 waves).
// Finishes BN stats redundantly from ps (L2-hot), then as round 6.
__global__ __launch_bounds__(512) void k_proj(const float* __restrict__ x,
                                              const float* __restrict__ ps,
                                              const float* __restrict__ gamma,
                                              const float* __restrict__ beta,
                                              const short* __restrict__ wf,
                                              short* __restrict__ qf,
                                              short* __restrict__ kf,
                                              short* __restrict__ vf) {
    __shared__ float xS[128][20];     // x tile (fp32), aliased later as vScr
    __shared__ float ssS[256];
    __shared__ short afS[8][256];     // act B-frags [ct][lane*4]
    int it = blockIdx.x, b = blockIdx.y;
    int t = threadIdx.x;
    if (t < 128) {
        int c = t;
        float4 p4 = *(const float4*)(ps + c * 4);
        float s1 = p4.x + p4.z;
        float s2 = p4.y + p4.w;
        float mean = s1 / (float)BHW;
        float var  = s2 / (float)BHW - mean * mean;
        float rstd = rsqrtf(var + 1e-5f);
        float sc = rstd * gamma[c];
        ssS[c]       = sc;
        ssS[128 + c] = beta[c] - mean * sc;
    }
    const float* xb = x + (size_t)b * CC * NN + it * 16;
    {
        int r = t >> 2, cf = t & 3;
        float4 v = *(const float4*)(xb + (size_t)r * NN + cf * 4);
        *(float4*)&xS[r][cf * 4] = v;
    }
    __syncthreads();
    {
        int ct = t >> 6, ln = t & 63;
        int hl_ = ln >> 4, li_ = ln & 15;
        int c0 = ct * 16 + 4 * hl_;
        bf4 r;
        #pragma unroll
        for (int jj = 0; jj < 4; ++jj) {
            int c = c0 + jj;
            float v = xS[c][li_] * ssS[c] + ssS[128 + c];
            v = 0.5f * v * (1.0f + erff(v * 0.70710678f));
            r[jj] = f2bf(v);
        }
        *(bf4*)&afS[ct][ln * 4] = r;
    }
    __syncthreads();

    int wid = t >> 6, lane = t & 63;
    int hl = lane >> 4, li = lane & 15;
    f32x4 acc[3];
    #pragma unroll
    for (int e = 0; e < 3; ++e) acc[e] = (f32x4)0.f;
    #pragma unroll
    for (int ct = 0; ct < 8; ++ct) {
        bf4 af = *(const bf4*)&afS[ct][lane * 4];
        #pragma unroll
        for (int e = 0; e < 3; ++e) {
            int mtp = wid * 3 + e, p = mtp >> 3, mt = mtp & 7;
            bf4 wfr = *(const bf4*)(wf + ((size_t)((p * 8 + mt) * 8 + ct) * 64 + lane) * 4);
            acc[e] = mfma16(wfr, af, acc[e]);
        }
    }
    int bq = b * 8;
    #pragma unroll
    for (int e = 0; e < 3; ++e) {
        int mtp = wid * 3 + e, p = mtp >> 3, h = mtp & 7;
        if (p < 2) {
            short* dst = (p == 0) ? qf : kf;
            bf4 r;
            #pragma unroll
            for (int jr = 0; jr < 4; ++jr) r[jr] = f2bf(acc[e][jr]);
            *(bf4*)&dst[(((size_t)(bq + h) * 64 + it) * 64 + lane) * 4] = r;
        }
    }
    float* vScr = &xS[0][0];
    __syncthreads();
    #pragma unroll
    for (int e = 0; e < 3; ++e) {
        int mtp = wid * 3 + e;
        if (mtp >= 16) {
            int h = mtp & 7;
            #pragma unroll
            for (int r = 0; r < 4; ++r)
                vScr[(h * 16 + 4 * hl + r) * 17 + li] = acc[e][r];
        }
    }
    __syncthreads();
    {
        int hh = wid;
        bf4 r;
        #pragma unroll
        for (int jj = 0; jj < 4; ++jj)
            r[jj] = f2bf(vScr[(hh * 16 + li) * 17 + 4 * hl + jj]);
        *(bf4*)&vf[(((size_t)(bq + hh) * 64 + it) * 64 + lane) * 4] = r;
    }
}

// ---------------- K3: one-pass attention, K head in LDS -----------------
// round-6 structure + dependency-chain fixes: lsum as f32x4 (4 chains),
// oacc split into two accumulators (2x32 MFMA chains instead of 1x64).
__global__ __launch_bounds__(256, 4) void k_attn(const short* __restrict__ qf,
                                                 const short* __restrict__ kf,
                                                 const short* __restrict__ vf,
                                                 const float* __restrict__ x,
                                                 const float* __restrict__ peh,
                                                 const float* __restrict__ pew,
                                                 float* __restrict__ out) {
    __shared__ short ldsK[16384];
    __shared__ float phS[64], pwS[64], redS[4];
    int t = threadIdx.x;
    int bh = blockIdx.x;
    const short* qfh = qf + (size_t)bh * 16384;
    const short* kfh = kf + (size_t)bh * 16384;
    const short* vfh = vf + (size_t)bh * 16384;

    #pragma unroll
    for (int k = 0; k < 8; ++k)
        ((int4*)ldsK)[t + 256 * k] = ((const int4*)kfh)[t + 256 * k];
    if (t < 64) {
        phS[t] = (t < 63) ? peh[t] * LOG2E : -1e30f;
        pwS[t] = (t < 63) ? pew[t] * LOG2E : -1e30f;
    }
    __syncthreads();

    int wid = t >> 6, lane = t & 63;
    int li = lane & 15, hl = lane >> 4;
    int it = blockIdx.y * 4 + wid;

    float knm = 0.f;
    #pragma unroll 4
    for (int jt2 = wid * 16; jt2 < wid * 16 + 16; ++jt2) {
        bf4 kb = *(const bf4*)&ldsK[jt2 * 256 + lane * 4];
        float s = 0.f;
        #pragma unroll
        for (int jj = 0; jj < 4; ++jj) {
            float kv = bf2f(kb[jj]);
            s = fmaf(kv, kv, s);
        }
        s += __shfl_xor(s, 16);
        s += __shfl_xor(s, 32);
        knm = fmaxf(knm, s);
    }
    knm = fmaxf(knm, __shfl_xor(knm, 1));
    knm = fmaxf(knm, __shfl_xor(knm, 2));
    knm = fmaxf(knm, __shfl_xor(knm, 4));
    knm = fmaxf(knm, __shfl_xor(knm, 8));
    if (lane == 0) redS[wid] = knm;
    __syncthreads();
    float kmax = sqrtf(fmaxf(fmaxf(redS[0], redS[1]), fmaxf(redS[2], redS[3])));

    float mph = phS[lane], mpw = pwS[lane];
    #pragma unroll
    for (int off = 32; off >= 1; off >>= 1) {
        mph = fmaxf(mph, __shfl_xor(mph, off));
        mpw = fmaxf(mpw, __shfl_xor(mpw, off));
    }
    float biasmax = mph + mpw;

    bf4 qfr = *(const bf4*)(qfh + ((size_t)it * 64 + lane) * 4);
    float qn2 = 0.f;
    #pragma unroll
    for (int jj = 0; jj < 4; ++jj) {
        float qv = bf2f(qfr[jj]);
        qn2 = fmaf(qv, qv, qn2);
    }
    qn2 += __shfl_xor(qn2, 16);
    qn2 += __shfl_xor(qn2, 32);
    float Mi = sqrtf(qn2) * kmax + biasmax;

    int wi = ((it & 1) << 4) | li;
    float pwm[2][4];
    #pragma unroll
    for (int jp = 0; jp < 2; ++jp)
        #pragma unroll
        for (int r = 0; r < 4; ++r)
            pwm[jp][r] = pwS[wi + 31 - ((jp << 4) + 4 * hl + r)] - Mi;

    int hq = it >> 1;
    f32x4 oaccA = (f32x4)0.f, oaccB = (f32x4)0.f;
    f32x4 lsum4 = (f32x4)0.f;

    bf4 vA[4], vB[4];
    auto loadV = [&](bf4* vb, int ch) {
        const short* vp = vfh + ((size_t)ch * 4 * 64 + lane) * 4;
        #pragma unroll
        for (int jt = 0; jt < 4; ++jt)
            vb[jt] = *(const bf4*)(vp + jt * 256);
    };
    auto compute = [&](bf4* vb, int ch) {
        float ph0 = phS[hq + 31 - 2 * ch];
        float ph1 = phS[hq + 30 - 2 * ch];
        f32x4 s[4];
        #pragma unroll
        for (int jt = 0; jt < 4; ++jt) {
            bf4 kb = *(const bf4*)&ldsK[(ch * 4 + jt) * 256 + lane * 4];
            float ph = (jt < 2) ? ph0 : ph1;
            f32x4 c;
            #pragma unroll
            for (int r = 0; r < 4; ++r) c[r] = pwm[jt & 1][r] + ph;
            s[jt] = mfma16(kb, qfr, c);
        }
        #pragma unroll
        for (int jt = 0; jt < 4; ++jt)
            #pragma unroll
            for (int r = 0; r < 4; ++r)
                s[jt][r] = exp2f(s[jt][r]);
        #pragma unroll
        for (int jt = 0; jt < 4; ++jt)
            #pragma unroll
            for (int r = 0; r < 4; ++r)
                lsum4[r] += s[jt][r];
        bf4 pf[4];
        #pragma unroll
        for (int jt = 0; jt < 4; ++jt) {
            unsigned lo = __builtin_amdgcn_perm(fbits(s[jt][1]), fbits(s[jt][0]), 0x07060302u);
            unsigned hi = __builtin_amdgcn_perm(fbits(s[jt][3]), fbits(s[jt][2]), 0x07060302u);
            unsigned pk[2] = {lo, hi};
            __builtin_memcpy(&pf[jt], pk, 8);
        }
        oaccA = mfma16(vb[0], pf[0], oaccA);
        oaccB = mfma16(vb[2], pf[2], oaccB);
        oaccA = mfma16(vb[1], pf[1], oaccA);
        oaccB = mfma16(vb[3], pf[3], oaccB);
    };

    loadV(vA, 0);
    #pragma unroll 1
    for (int ch = 0; ch < 16; ch += 2) {
        loadV(vB, ch + 1);
        compute(vA, ch);
        if (ch + 2 < 16) loadV(vA, ch + 2);
        compute(vB, ch + 1);
    }

    float lsum = (lsum4[0] + lsum4[1]) + (lsum4[2] + lsum4[3]);
    lsum += __shfl_xor(lsum, 16);
    lsum += __shfl_xor(lsum, 32);
    float rl = 1.0f / lsum;

    int b = bh >> 3, h = bh & 7;
    size_t base = (size_t)b * (CC * NN) + (size_t)h * KD * NN;
    int i = it * 16 + li;
    #pragma unroll
    for (int r = 0; r < 4; ++r) {
        int d = 4 * hl + r;
        size_t g = base + (size_t)d * NN + i;
        out[g] = x[g] + (oaccA[r] + oaccB[r]) * rl;
    }
}

extern "C" void kernel_launch(void* const* d_in, const int* in_sizes, int n_in,
                              void* d_out, int out_size, void* d_ws, size_t ws_size,
                              hipStream_t stream) {
    const float* x     = (const float*)d_in[0];
    const float* gamma = (const float*)d_in[1];
    const float* beta  = (const float*)d_in[2];
    const float* wq    = (const float*)d_in[3];
    const float* wk    = (const float*)d_in[4];
    const float* wv    = (const float*)d_in[5];
    const float* peh   = (const float*)d_in[6];
    const float* pew   = (const float*)d_in[7];
    float* out = (float*)d_out;
    float* ws  = (float*)d_ws;

    float* ps = ws;                          // 512 f32 partial sums
    short* wf = (short*)(ws + 512);          // 49152 shorts: W bf16 frags
    short* qf = wf + 49152;                  // 1M shorts each (2 MB)
    short* kf = qf + (1 << 20);
    short* vf = kf + (1 << 20);
    float* out2 = (float*)(vf + (1 << 20));  // 1M f32: attn-duplicate scratch

    k_prep<<<304, 256, 0, stream>>>(x, wq, wk, wv, ps, wf);
    k_proj<<<dim3(64, 8), 512, 0, stream>>>(x, ps, gamma, beta, wf, qf, kf, vf);
    k_attn<<<dim3(64, 16), 256, 0, stream>>>(qf, kf, vf, x, peh, pew, out);
    // timing probe: exact duplicate -> scratch; dur delta across rounds = attn cost
    k_attn<<<dim3(64, 16), 256, 0, stream>>>(qf, kf, vf, x, peh, pew, out2);
}

// Round 10
// 42.943 us; speedup vs baseline: 3.3301x; 1.5548x over previous
//
#include <hip/hip_runtime.h>
#include <hip/hip_bf16.h>
#include <math.h>

typedef short bf4 __attribute__((ext_vector_type(4)));
typedef float f32x4 __attribute__((ext_vector_type(4)));

constexpr int CC  = 128;
constexpr int NH  = 8;
constexpr int KD  = 16;
constexpr int BB  = 8;
constexpr int NN  = 1024;
constexpr int BHW = BB * NN;
constexpr float LOG2E = 1.44269504088896340736f;

static __device__ __forceinline__ short f2bf(float x) {
    __hip_bfloat16 b = __float2bfloat16(x);
    short s;
    __builtin_memcpy(&s, &b, 2);
    return s;
}
static __device__ __forceinline__ float bf2f(short s) {
    unsigned u = ((unsigned)(unsigned short)s) << 16;
    float f;
    __builtin_memcpy(&f, &u, 4);
    return f;
}
static __device__ __forceinline__ unsigned fbits(float x) {
    unsigned u;
    __builtin_memcpy(&u, &x, 4);
    return u;
}

static __device__ __forceinline__ f32x4 mfma16(bf4 a, bf4 b, f32x4 c) {
#if __has_builtin(__builtin_amdgcn_mfma_f32_16x16x16bf16_1k)
    return __builtin_amdgcn_mfma_f32_16x16x16bf16_1k(a, b, c, 0, 0, 0);
#else
    f32x4 d;
    asm volatile("v_mfma_f32_16x16x16_bf16 %0, %1, %2, %3"
                 : "=&v"(d) : "v"(a), "v"(b), "v"(c));
    return d;
#endif
}

// ---------------- K1: BN partial stats (2-way split) + W->bf16 frags ----
__global__ __launch_bounds__(256) void k_prep(const float* __restrict__ x,
                                              const float* __restrict__ wq,
                                              const float* __restrict__ wk,
                                              const float* __restrict__ wv,
                                              float* __restrict__ ps,
                                              short* __restrict__ wf) {
    int t = threadIdx.x;
    int blk = blockIdx.x;
    if (blk < 256) {
        int c = blk >> 1, half = blk & 1;
        float s1 = 0.f, s2 = 0.f;
        #pragma unroll
        for (int k = 0; k < 4; ++k) {
            int b = half * 4 + k;
            float4 v = ((const float4*)(x + ((size_t)b * CC + c) * NN))[t];
            s1 += v.x + v.y + v.z + v.w;
            s2 += v.x * v.x + v.y * v.y + v.z * v.z + v.w * v.w;
        }
        #pragma unroll
        for (int off = 32; off >= 1; off >>= 1) {
            s1 += __shfl_xor(s1, off);
            s2 += __shfl_xor(s2, off);
        }
        __shared__ float r1[4], r2[4];
        int wid = t >> 6, lane = t & 63;
        if (lane == 0) { r1[wid] = s1; r2[wid] = s2; }
        __syncthreads();
        if (t == 0) {
            ps[c * 4 + half * 2 + 0] = r1[0] + r1[1] + r1[2] + r1[3];
            ps[c * 4 + half * 2 + 1] = r2[0] + r2[1] + r2[2] + r2[3];
        }
    } else {
        // Wf[((p*8+mt)*8+ct)*64 + ln][jj] = W_p[mt*16+li][ct*16+4*hl+jj]
        int s = (blk - 256) * 256 + t;   // 0..12287
        int ln = s & 63, ct = (s >> 6) & 7, mt = (s >> 9) & 7, p = s >> 12;
        int hl = ln >> 4, li = ln & 15;
        const float* w = (p == 0) ? wq : (p == 1) ? wk : wv;
        float4 v = *(const float4*)(w + (size_t)(mt * 16 + li) * CC + ct * 16 + 4 * hl);
        float sc = (p == 0) ? 0.25f * LOG2E : 1.0f;
        bf4 r;
        r[0] = f2bf(v.x * sc); r[1] = f2bf(v.y * sc);
        r[2] = f2bf(v.z * sc); r[3] = f2bf(v.w * sc);
        *(bf4*)&wf[(size_t)s * 4] = r;
    }
}

// ---------------- K2: fused BN+GELU + QKV projection via MFMA -----------
__global__ __launch_bounds__(512) void k_proj(const float* __restrict__ x,
                                              const float* __restrict__ ps,
                                              const float* __restrict__ gamma,
                                              const float* __restrict__ beta,
                                              const short* __restrict__ wf,
                                              short* __restrict__ qf,
                                              short* __restrict__ kf,
                                              short* __restrict__ vf) {
    __shared__ float xS[128][20];
    __shared__ float ssS[256];
    __shared__ short afS[8][256];
    int it = blockIdx.x, b = blockIdx.y;
    int t = threadIdx.x;
    if (t < 128) {
        int c = t;
        float4 p4 = *(const float4*)(ps + c * 4);
        float s1 = p4.x + p4.z;
        float s2 = p4.y + p4.w;
        float mean = s1 / (float)BHW;
        float var  = s2 / (float)BHW - mean * mean;
        float rstd = rsqrtf(var + 1e-5f);
        float sc = rstd * gamma[c];
        ssS[c]       = sc;
        ssS[128 + c] = beta[c] - mean * sc;
    }
    const float* xb = x + (size_t)b * CC * NN + it * 16;
    {
        int r = t >> 2, cf = t & 3;
        float4 v = *(const float4*)(xb + (size_t)r * NN + cf * 4);
        *(float4*)&xS[r][cf * 4] = v;
    }
    __syncthreads();
    {
        int ct = t >> 6, ln = t & 63;
        int hl_ = ln >> 4, li_ = ln & 15;
        int c0 = ct * 16 + 4 * hl_;
        bf4 r;
        #pragma unroll
        for (int jj = 0; jj < 4; ++jj) {
            int c = c0 + jj;
            float v = xS[c][li_] * ssS[c] + ssS[128 + c];
            v = 0.5f * v * (1.0f + erff(v * 0.70710678f));
            r[jj] = f2bf(v);
        }
        *(bf4*)&afS[ct][ln * 4] = r;
    }
    __syncthreads();

    int wid = t >> 6, lane = t & 63;
    int hl = lane >> 4, li = lane & 15;
    f32x4 acc[3];
    #pragma unroll
    for (int e = 0; e < 3; ++e) acc[e] = (f32x4)0.f;
    #pragma unroll
    for (int ct = 0; ct < 8; ++ct) {
        bf4 af = *(const bf4*)&afS[ct][lane * 4];
        #pragma unroll
        for (int e = 0; e < 3; ++e) {
            int mtp = wid * 3 + e, p = mtp >> 3, mt = mtp & 7;
            bf4 wfr = *(const bf4*)(wf + ((size_t)((p * 8 + mt) * 8 + ct) * 64 + lane) * 4);
            acc[e] = mfma16(wfr, af, acc[e]);
        }
    }
    int bq = b * 8;
    #pragma unroll
    for (int e = 0; e < 3; ++e) {
        int mtp = wid * 3 + e, p = mtp >> 3, h = mtp & 7;
        if (p < 2) {
            short* dst = (p == 0) ? qf : kf;
            bf4 r;
            #pragma unroll
            for (int jr = 0; jr < 4; ++jr) r[jr] = f2bf(acc[e][jr]);
            *(bf4*)&dst[(((size_t)(bq + h) * 64 + it) * 64 + lane) * 4] = r;
        }
    }
    float* vScr = &xS[0][0];
    __syncthreads();
    #pragma unroll
    for (int e = 0; e < 3; ++e) {
        int mtp = wid * 3 + e;
        if (mtp >= 16) {
            int h = mtp & 7;
            #pragma unroll
            for (int r = 0; r < 4; ++r)
                vScr[(h * 16 + 4 * hl + r) * 17 + li] = acc[e][r];
        }
    }
    __syncthreads();
    {
        int hh = wid;
        bf4 r;
        #pragma unroll
        for (int jj = 0; jj < 4; ++jj)
            r[jj] = f2bf(vScr[(hh * 16 + li) * 17 + 4 * hl + jj]);
        *(bf4*)&vf[(((size_t)(bq + hh) * 64 + it) * 64 + lane) * 4] = r;
    }
}

// ---------------- K3: one-pass attention, fully pipelined ---------------
// K head in LDS; BOTH K (from LDS) and V (from global) register
// double-buffered one chunk ahead -> no demand ds_read/load in compute.
__global__ __launch_bounds__(256, 4) void k_attn(const short* __restrict__ qf,
                                                 const short* __restrict__ kf,
                                                 const short* __restrict__ vf,
                                                 const float* __restrict__ x,
                                                 const float* __restrict__ peh,
                                                 const float* __restrict__ pew,
                                                 float* __restrict__ out) {
    __shared__ short ldsK[16384];
    __shared__ float phS[64], pwS[64], redS[4];
    int t = threadIdx.x;
    int bh = blockIdx.x;
    const short* qfh = qf + (size_t)bh * 16384;
    const short* kfh = kf + (size_t)bh * 16384;
    const short* vfh = vf + (size_t)bh * 16384;

    #pragma unroll
    for (int k = 0; k < 8; ++k)
        ((int4*)ldsK)[t + 256 * k] = ((const int4*)kfh)[t + 256 * k];
    if (t < 64) {
        phS[t] = (t < 63) ? peh[t] * LOG2E : -1e30f;
        pwS[t] = (t < 63) ? pew[t] * LOG2E : -1e30f;
    }
    __syncthreads();

    int wid = t >> 6, lane = t & 63;
    int li = lane & 15, hl = lane >> 4;
    int it = blockIdx.y * 4 + wid;

    float knm = 0.f;
    #pragma unroll 4
    for (int jt2 = wid * 16; jt2 < wid * 16 + 16; ++jt2) {
        bf4 kb = *(const bf4*)&ldsK[jt2 * 256 + lane * 4];
        float s = 0.f;
        #pragma unroll
        for (int jj = 0; jj < 4; ++jj) {
            float kv = bf2f(kb[jj]);
            s = fmaf(kv, kv, s);
        }
        s += __shfl_xor(s, 16);
        s += __shfl_xor(s, 32);
        knm = fmaxf(knm, s);
    }
    knm = fmaxf(knm, __shfl_xor(knm, 1));
    knm = fmaxf(knm, __shfl_xor(knm, 2));
    knm = fmaxf(knm, __shfl_xor(knm, 4));
    knm = fmaxf(knm, __shfl_xor(knm, 8));
    if (lane == 0) redS[wid] = knm;
    __syncthreads();
    float kmax = sqrtf(fmaxf(fmaxf(redS[0], redS[1]), fmaxf(redS[2], redS[3])));

    float mph = phS[lane], mpw = pwS[lane];
    #pragma unroll
    for (int off = 32; off >= 1; off >>= 1) {
        mph = fmaxf(mph, __shfl_xor(mph, off));
        mpw = fmaxf(mpw, __shfl_xor(mpw, off));
    }
    float biasmax = mph + mpw;

    bf4 qfr = *(const bf4*)(qfh + ((size_t)it * 64 + lane) * 4);
    float qn2 = 0.f;
    #pragma unroll
    for (int jj = 0; jj < 4; ++jj) {
        float qv = bf2f(qfr[jj]);
        qn2 = fmaf(qv, qv, qn2);
    }
    qn2 += __shfl_xor(qn2, 16);
    qn2 += __shfl_xor(qn2, 32);
    float Mi = sqrtf(qn2) * kmax + biasmax;

    int wi = ((it & 1) << 4) | li;
    float pwm[2][4];
    #pragma unroll
    for (int jp = 0; jp < 2; ++jp)
        #pragma unroll
        for (int r = 0; r < 4; ++r)
            pwm[jp][r] = pwS[wi + 31 - ((jp << 4) + 4 * hl + r)] - Mi;

    int hq = it >> 1;
    f32x4 oaccA = (f32x4)0.f, oaccB = (f32x4)0.f;
    f32x4 lsum4 = (f32x4)0.f;

    bf4 kA[4], kB[4], vA[4], vB[4];
    auto kload = [&](bf4* kb, int ch) {
        #pragma unroll
        for (int jt = 0; jt < 4; ++jt)
            kb[jt] = *(const bf4*)&ldsK[(ch * 4 + jt) * 256 + lane * 4];
    };
    auto vload = [&](bf4* vb, int ch) {
        const short* vp = vfh + ((size_t)ch * 4 * 64 + lane) * 4;
        #pragma unroll
        for (int jt = 0; jt < 4; ++jt)
            vb[jt] = *(const bf4*)(vp + jt * 256);
    };
    auto compute = [&](bf4* kb, bf4* vb, int ch) {
        float ph0 = phS[hq + 31 - 2 * ch];
        float ph1 = phS[hq + 30 - 2 * ch];
        f32x4 s[4];
        #pragma unroll
        for (int jt = 0; jt < 4; ++jt) {
            float ph = (jt < 2) ? ph0 : ph1;
            f32x4 c;
            #pragma unroll
            for (int r = 0; r < 4; ++r) c[r] = pwm[jt & 1][r] + ph;
            s[jt] = mfma16(kb[jt], qfr, c);
        }
        #pragma unroll
        for (int jt = 0; jt < 4; ++jt)
            #pragma unroll
            for (int r = 0; r < 4; ++r)
                s[jt][r] = exp2f(s[jt][r]);
        #pragma unroll
        for (int jt = 0; jt < 4; ++jt)
            #pragma unroll
            for (int r = 0; r < 4; ++r)
                lsum4[r] += s[jt][r];
        bf4 pf[4];
        #pragma unroll
        for (int jt = 0; jt < 4; ++jt) {
            unsigned lo = __builtin_amdgcn_perm(fbits(s[jt][1]), fbits(s[jt][0]), 0x07060302u);
            unsigned hi = __builtin_amdgcn_perm(fbits(s[jt][3]), fbits(s[jt][2]), 0x07060302u);
            unsigned pk[2] = {lo, hi};
            __builtin_memcpy(&pf[jt], pk, 8);
        }
        oaccA = mfma16(vb[0], pf[0], oaccA);
        oaccB = mfma16(vb[2], pf[2], oaccB);
        oaccA = mfma16(vb[1], pf[1], oaccA);
        oaccB = mfma16(vb[3], pf[3], oaccB);
    };

    kload(kA, 0); vload(vA, 0);
    #pragma unroll 1
    for (int ch = 0; ch < 16; ch += 2) {
        kload(kB, ch + 1); vload(vB, ch + 1);
        compute(kA, vA, ch);
        if (ch + 2 < 16) { kload(kA, ch + 2); vload(vA, ch + 2); }
        compute(kB, vB, ch + 1);
    }

    float lsum = (lsum4[0] + lsum4[1]) + (lsum4[2] + lsum4[3]);
    lsum += __shfl_xor(lsum, 16);
    lsum += __shfl_xor(lsum, 32);
    float rl = 1.0f / lsum;

    int b = bh >> 3, h = bh & 7;
    size_t base = (size_t)b * (CC * NN) + (size_t)h * KD * NN;
    int i = it * 16 + li;
    #pragma unroll
    for (int r = 0; r < 4; ++r) {
        int d = 4 * hl + r;
        size_t g = base + (size_t)d * NN + i;
        out[g] = x[g] + (oaccA[r] + oaccB[r]) * rl;
    }
}

extern "C" void kernel_launch(void* const* d_in, const int* in_sizes, int n_in,
                              void* d_out, int out_size, void* d_ws, size_t ws_size,
                              hipStream_t stream) {
    const float* x     = (const float*)d_in[0];
    const float* gamma = (const float*)d_in[1];
    const float* beta  = (const float*)d_in[2];
    const float* wq    = (const float*)d_in[3];
    const float* wk    = (const float*)d_in[4];
    const float* wv    = (const float*)d_in[5];
    const float* peh   = (const float*)d_in[6];
    const float* pew   = (const float*)d_in[7];
    float* out = (float*)d_out;
    float* ws  = (float*)d_ws;

    float* ps = ws;                          // 512 f32 partial sums
    short* wf = (short*)(ws + 512);          // 49152 shorts: W bf16 frags
    short* qf = wf + 49152;                  // 1M shorts each (2 MB)
    short* kf = qf + (1 << 20);
    short* vf = kf + (1 << 20);

    k_prep<<<304, 256, 0, stream>>>(x, wq, wk, wv, ps, wf);
    k_proj<<<dim3(64, 8), 512, 0, stream>>>(x, ps, gamma, beta, wf, qf, kf, vf);
    k_attn<<<dim3(64, 16), 256, 0, stream>>>(qf, kf, vf, x, peh, pew, out);
}

// Round 11
// 34.625 us; speedup vs baseline: 4.1301x; 1.2402x over previous
//
#include <hip/hip_runtime.h>
#include <hip/hip_bf16.h>
#include <math.h>

typedef short bf4 __attribute__((ext_vector_type(4)));
typedef float f32x4 __attribute__((ext_vector_type(4)));

constexpr int CC  = 128;
constexpr int NH  = 8;
constexpr int KD  = 16;
constexpr int BB  = 8;
constexpr int NN  = 1024;
constexpr int BHW = BB * NN;
constexpr float LOG2E = 1.44269504088896340736f;

static __device__ __forceinline__ short f2bf(float x) {
    __hip_bfloat16 b = __float2bfloat16(x);
    short s;
    __builtin_memcpy(&s, &b, 2);
    return s;
}
static __device__ __forceinline__ float bf2f(short s) {
    unsigned u = ((unsigned)(unsigned short)s) << 16;
    float f;
    __builtin_memcpy(&f, &u, 4);
    return f;
}
static __device__ __forceinline__ unsigned fbits(float x) {
    unsigned u;
    __builtin_memcpy(&u, &x, 4);
    return u;
}
static __device__ __forceinline__ float fexp2(float x) {
#if __has_builtin(__builtin_amdgcn_exp2f)
    return __builtin_amdgcn_exp2f(x);   // raw v_exp_f32 (denormal flush fine here)
#else
    return exp2f(x);
#endif
}

static __device__ __forceinline__ f32x4 mfma16(bf4 a, bf4 b, f32x4 c) {
#if __has_builtin(__builtin_amdgcn_mfma_f32_16x16x16bf16_1k)
    return __builtin_amdgcn_mfma_f32_16x16x16bf16_1k(a, b, c, 0, 0, 0);
#else
    f32x4 d;
    asm volatile("v_mfma_f32_16x16x16_bf16 %0, %1, %2, %3"
                 : "=&v"(d) : "v"(a), "v"(b), "v"(c));
    return d;
#endif
}

// ---------------- K1: BN partial stats (2-way split) + W->bf16 frags ----
__global__ __launch_bounds__(256) void k_prep(const float* __restrict__ x,
                                              const float* __restrict__ wq,
                                              const float* __restrict__ wk,
                                              const float* __restrict__ wv,
                                              float* __restrict__ ps,
                                              short* __restrict__ wf) {
    int t = threadIdx.x;
    int blk = blockIdx.x;
    if (blk < 256) {
        int c = blk >> 1, half = blk & 1;
        float s1 = 0.f, s2 = 0.f;
        #pragma unroll
        for (int k = 0; k < 4; ++k) {
            int b = half * 4 + k;
            float4 v = ((const float4*)(x + ((size_t)b * CC + c) * NN))[t];
            s1 += v.x + v.y + v.z + v.w;
            s2 += v.x * v.x + v.y * v.y + v.z * v.z + v.w * v.w;
        }
        #pragma unroll
        for (int off = 32; off >= 1; off >>= 1) {
            s1 += __shfl_xor(s1, off);
            s2 += __shfl_xor(s2, off);
        }
        __shared__ float r1[4], r2[4];
        int wid = t >> 6, lane = t & 63;
        if (lane == 0) { r1[wid] = s1; r2[wid] = s2; }
        __syncthreads();
        if (t == 0) {
            ps[c * 4 + half * 2 + 0] = r1[0] + r1[1] + r1[2] + r1[3];
            ps[c * 4 + half * 2 + 1] = r2[0] + r2[1] + r2[2] + r2[3];
        }
    } else {
        // Wf[((p*8+mt)*8+ct)*64 + ln][jj] = W_p[mt*16+li][ct*16+4*hl+jj]
        int s = (blk - 256) * 256 + t;   // 0..12287
        int ln = s & 63, ct = (s >> 6) & 7, mt = (s >> 9) & 7, p = s >> 12;
        int hl = ln >> 4, li = ln & 15;
        const float* w = (p == 0) ? wq : (p == 1) ? wk : wv;
        float4 v = *(const float4*)(w + (size_t)(mt * 16 + li) * CC + ct * 16 + 4 * hl);
        float sc = (p == 0) ? 0.25f * LOG2E : 1.0f;
        bf4 r;
        r[0] = f2bf(v.x * sc); r[1] = f2bf(v.y * sc);
        r[2] = f2bf(v.z * sc); r[3] = f2bf(v.w * sc);
        *(bf4*)&wf[(size_t)s * 4] = r;
    }
}

// ---------------- K2: fused BN+GELU + QKV projection via MFMA -----------
__global__ __launch_bounds__(512) void k_proj(const float* __restrict__ x,
                                              const float* __restrict__ ps,
                                              const float* __restrict__ gamma,
                                              const float* __restrict__ beta,
                                              const short* __restrict__ wf,
                                              short* __restrict__ qf,
                                              short* __restrict__ kf,
                                              short* __restrict__ vf) {
    __shared__ float xS[128][20];
    __shared__ float ssS[256];
    __shared__ short afS[8][256];
    int it = blockIdx.x, b = blockIdx.y;
    int t = threadIdx.x;
    if (t < 128) {
        int c = t;
        float4 p4 = *(const float4*)(ps + c * 4);
        float s1 = p4.x + p4.z;
        float s2 = p4.y + p4.w;
        float mean = s1 / (float)BHW;
        float var  = s2 / (float)BHW - mean * mean;
        float rstd = rsqrtf(var + 1e-5f);
        float sc = rstd * gamma[c];
        ssS[c]       = sc;
        ssS[128 + c] = beta[c] - mean * sc;
    }
    const float* xb = x + (size_t)b * CC * NN + it * 16;
    {
        int r = t >> 2, cf = t & 3;
        float4 v = *(const float4*)(xb + (size_t)r * NN + cf * 4);
        *(float4*)&xS[r][cf * 4] = v;
    }
    __syncthreads();
    {
        int ct = t >> 6, ln = t & 63;
        int hl_ = ln >> 4, li_ = ln & 15;
        int c0 = ct * 16 + 4 * hl_;
        bf4 r;
        #pragma unroll
        for (int jj = 0; jj < 4; ++jj) {
            int c = c0 + jj;
            float v = xS[c][li_] * ssS[c] + ssS[128 + c];
            v = 0.5f * v * (1.0f + erff(v * 0.70710678f));
            r[jj] = f2bf(v);
        }
        *(bf4*)&afS[ct][ln * 4] = r;
    }
    __syncthreads();

    int wid = t >> 6, lane = t & 63;
    int hl = lane >> 4, li = lane & 15;
    f32x4 acc[3];
    #pragma unroll
    for (int e = 0; e < 3; ++e) acc[e] = (f32x4)0.f;
    #pragma unroll
    for (int ct = 0; ct < 8; ++ct) {
        bf4 af = *(const bf4*)&afS[ct][lane * 4];
        #pragma unroll
        for (int e = 0; e < 3; ++e) {
            int mtp = wid * 3 + e, p = mtp >> 3, mt = mtp & 7;
            bf4 wfr = *(const bf4*)(wf + ((size_t)((p * 8 + mt) * 8 + ct) * 64 + lane) * 4);
            acc[e] = mfma16(wfr, af, acc[e]);
        }
    }
    int bq = b * 8;
    #pragma unroll
    for (int e = 0; e < 3; ++e) {
        int mtp = wid * 3 + e, p = mtp >> 3, h = mtp & 7;
        if (p < 2) {
            short* dst = (p == 0) ? qf : kf;
            bf4 r;
            #pragma unroll
            for (int jr = 0; jr < 4; ++jr) r[jr] = f2bf(acc[e][jr]);
            *(bf4*)&dst[(((size_t)(bq + h) * 64 + it) * 64 + lane) * 4] = r;
        }
    }
    float* vScr = &xS[0][0];
    __syncthreads();
    #pragma unroll
    for (int e = 0; e < 3; ++e) {
        int mtp = wid * 3 + e;
        if (mtp >= 16) {
            int h = mtp & 7;
            #pragma unroll
            for (int r = 0; r < 4; ++r)
                vScr[(h * 16 + 4 * hl + r) * 17 + li] = acc[e][r];
        }
    }
    __syncthreads();
    {
        int hh = wid;
        bf4 r;
        #pragma unroll
        for (int jj = 0; jj < 4; ++jj)
            r[jj] = f2bf(vScr[(hh * 16 + li) * 17 + 4 * hl + jj]);
        *(bf4*)&vf[(((size_t)(bq + hh) * 64 + it) * 64 + lane) * 4] = r;
    }
}

// ---------------- K3: one-pass attention, K AND V heads in LDS ----------
// grid (64, 8), block 512 (8 waves, one 16-query i-tile each). K+V (64 KB)
// staged once per block with bulk int4 copies; hot loop reads only LDS,
// register double-buffered one chunk ahead. Native v_exp_f32.
__global__ __launch_bounds__(512) void k_attn(const short* __restrict__ qf,
                                              const short* __restrict__ kf,
                                              const short* __restrict__ vf,
                                              const float* __restrict__ x,
                                              const float* __restrict__ peh,
                                              const float* __restrict__ pew,
                                              float* __restrict__ out) {
    __shared__ short ldsK[16384];   // 32 KB
    __shared__ short ldsV[16384];   // 32 KB
    __shared__ float phS[64], pwS[64], redS[8];
    int t = threadIdx.x;
    int bh = blockIdx.x;
    const short* qfh = qf + (size_t)bh * 16384;
    const short* kfh = kf + (size_t)bh * 16384;
    const short* vfh = vf + (size_t)bh * 16384;

    #pragma unroll
    for (int k = 0; k < 4; ++k)
        ((int4*)ldsK)[t + 512 * k] = ((const int4*)kfh)[t + 512 * k];
    #pragma unroll
    for (int k = 0; k < 4; ++k)
        ((int4*)ldsV)[t + 512 * k] = ((const int4*)vfh)[t + 512 * k];
    if (t < 64) {
        phS[t] = (t < 63) ? peh[t] * LOG2E : -1e30f;
        pwS[t] = (t < 63) ? pew[t] * LOG2E : -1e30f;
    }
    __syncthreads();

    int wid = t >> 6, lane = t & 63;
    int li = lane & 15, hl = lane >> 4;
    int it = blockIdx.y * 8 + wid;

    // kmax scan from LDS: wave covers 8 j-tiles
    float knm = 0.f;
    #pragma unroll 4
    for (int jt2 = wid * 8; jt2 < wid * 8 + 8; ++jt2) {
        bf4 kb = *(const bf4*)&ldsK[jt2 * 256 + lane * 4];
        float s = 0.f;
        #pragma unroll
        for (int jj = 0; jj < 4; ++jj) {
            float kv = bf2f(kb[jj]);
            s = fmaf(kv, kv, s);
        }
        s += __shfl_xor(s, 16);
        s += __shfl_xor(s, 32);
        knm = fmaxf(knm, s);
    }
    knm = fmaxf(knm, __shfl_xor(knm, 1));
    knm = fmaxf(knm, __shfl_xor(knm, 2));
    knm = fmaxf(knm, __shfl_xor(knm, 4));
    knm = fmaxf(knm, __shfl_xor(knm, 8));
    if (lane == 0) redS[wid] = knm;
    __syncthreads();
    float kmax = fmaxf(fmaxf(fmaxf(redS[0], redS[1]), fmaxf(redS[2], redS[3])),
                       fmaxf(fmaxf(redS[4], redS[5]), fmaxf(redS[6], redS[7])));
    kmax = sqrtf(kmax);

    float mph = phS[lane], mpw = pwS[lane];
    #pragma unroll
    for (int off = 32; off >= 1; off >>= 1) {
        mph = fmaxf(mph, __shfl_xor(mph, off));
        mpw = fmaxf(mpw, __shfl_xor(mpw, off));
    }
    float biasmax = mph + mpw;

    bf4 qfr = *(const bf4*)(qfh + ((size_t)it * 64 + lane) * 4);
    float qn2 = 0.f;
    #pragma unroll
    for (int jj = 0; jj < 4; ++jj) {
        float qv = bf2f(qfr[jj]);
        qn2 = fmaf(qv, qv, qn2);
    }
    qn2 += __shfl_xor(qn2, 16);
    qn2 += __shfl_xor(qn2, 32);
    float Mi = sqrtf(qn2) * kmax + biasmax;

    int wi = ((it & 1) << 4) | li;
    float pwm[2][4];
    #pragma unroll
    for (int jp = 0; jp < 2; ++jp)
        #pragma unroll
        for (int r = 0; r < 4; ++r)
            pwm[jp][r] = pwS[wi + 31 - ((jp << 4) + 4 * hl + r)] - Mi;

    int hq = it >> 1;
    f32x4 oaccA = (f32x4)0.f, oaccB = (f32x4)0.f;
    f32x4 lsum4 = (f32x4)0.f;

    bf4 kA[4], kB[4], vA[4], vB[4];
    auto kload = [&](bf4* kb, int ch) {
        #pragma unroll
        for (int jt = 0; jt < 4; ++jt)
            kb[jt] = *(const bf4*)&ldsK[(ch * 4 + jt) * 256 + lane * 4];
    };
    auto vload = [&](bf4* vb, int ch) {
        #pragma unroll
        for (int jt = 0; jt < 4; ++jt)
            vb[jt] = *(const bf4*)&ldsV[(ch * 4 + jt) * 256 + lane * 4];
    };
    auto compute = [&](bf4* kb, bf4* vb, int ch) {
        float ph0 = phS[hq + 31 - 2 * ch];
        float ph1 = phS[hq + 30 - 2 * ch];
        f32x4 s[4];
        #pragma unroll
        for (int jt = 0; jt < 4; ++jt) {
            float ph = (jt < 2) ? ph0 : ph1;
            f32x4 c;
            #pragma unroll
            for (int r = 0; r < 4; ++r) c[r] = pwm[jt & 1][r] + ph;
            s[jt] = mfma16(kb[jt], qfr, c);
        }
        #pragma unroll
        for (int jt = 0; jt < 4; ++jt)
            #pragma unroll
            for (int r = 0; r < 4; ++r)
                s[jt][r] = fexp2(s[jt][r]);
        #pragma unroll
        for (int jt = 0; jt < 4; ++jt)
            #pragma unroll
            for (int r = 0; r < 4; ++r)
                lsum4[r] += s[jt][r];
        bf4 pf[4];
        #pragma unroll
        for (int jt = 0; jt < 4; ++jt) {
            unsigned lo = __builtin_amdgcn_perm(fbits(s[jt][1]), fbits(s[jt][0]), 0x07060302u);
            unsigned hi = __builtin_amdgcn_perm(fbits(s[jt][3]), fbits(s[jt][2]), 0x07060302u);
            unsigned pk[2] = {lo, hi};
            __builtin_memcpy(&pf[jt], pk, 8);
        }
        oaccA = mfma16(vb[0], pf[0], oaccA);
        oaccB = mfma16(vb[2], pf[2], oaccB);
        oaccA = mfma16(vb[1], pf[1], oaccA);
        oaccB = mfma16(vb[3], pf[3], oaccB);
    };

    kload(kA, 0); vload(vA, 0);
    #pragma unroll 1
    for (int ch = 0; ch < 16; ch += 2) {
        kload(kB, ch + 1); vload(vB, ch + 1);
        compute(kA, vA, ch);
        if (ch + 2 < 16) { kload(kA, ch + 2); vload(vA, ch + 2); }
        compute(kB, vB, ch + 1);
    }

    float lsum = (lsum4[0] + lsum4[1]) + (lsum4[2] + lsum4[3]);
    lsum += __shfl_xor(lsum, 16);
    lsum += __shfl_xor(lsum, 32);
    float rl = 1.0f / lsum;

    int b = bh >> 3, h = bh & 7;
    size_t base = (size_t)b * (CC * NN) + (size_t)h * KD * NN;
    int i = it * 16 + li;
    #pragma unroll
    for (int r = 0; r < 4; ++r) {
        int d = 4 * hl + r;
        size_t g = base + (size_t)d * NN + i;
        out[g] = x[g] + (oaccA[r] + oaccB[r]) * rl;
    }
}

extern "C" void kernel_launch(void* const* d_in, const int* in_sizes, int n_in,
                              void* d_out, int out_size, void* d_ws, size_t ws_size,
                              hipStream_t stream) {
    const float* x     = (const float*)d_in[0];
    const float* gamma = (const float*)d_in[1];
    const float* beta  = (const float*)d_in[2];
    const float* wq    = (const float*)d_in[3];
    const float* wk    = (const float*)d_in[4];
    const float* wv    = (const float*)d_in[5];
    const float* peh   = (const float*)d_in[6];
    const float* pew   = (const float*)d_in[7];
    float* out = (float*)d_out;
    float* ws  = (float*)d_ws;

    float* ps = ws;                          // 512 f32 partial sums
    short* wf = (short*)(ws + 512);          // 49152 shorts: W bf16 frags
    short* qf = wf + 49152;                  // 1M shorts each (2 MB)
    short* kf = qf + (1 << 20);
    short* vf = kf + (1 << 20);

    k_prep<<<304, 256, 0, stream>>>(x, wq, wk, wv, ps, wf);
    k_proj<<<dim3(64, 8), 512, 0, stream>>>(x, ps, gamma, beta, wf, qf, kf, vf);
    k_attn<<<dim3(64, 8), 512, 0, stream>>>(qf, kf, vf, x, peh, pew, out);
}

// Round 12
// 33.850 us; speedup vs baseline: 4.2247x; 1.0229x over previous
//
#include <hip/hip_runtime.h>
#include <hip/hip_bf16.h>
#include <math.h>

typedef short bf4 __attribute__((ext_vector_type(4)));
typedef float f32x4 __attribute__((ext_vector_type(4)));

constexpr int CC  = 128;
constexpr int NH  = 8;
constexpr int KD  = 16;
constexpr int BB  = 8;
constexpr int NN  = 1024;
constexpr int BHW = BB * NN;
constexpr float LOG2E = 1.44269504088896340736f;
// Softmax shift: any per-query constant works exactly (P and l scale by the
// same 2^delta). Scores are ~+-3 in log2 domain; 32 gives ~2^100 margin
// against bf16 overflow (needs < s*+127) and underflow (needs > s-126).
constexpr float MBOUND = 32.0f;

static __device__ __forceinline__ short f2bf(float x) {
    __hip_bfloat16 b = __float2bfloat16(x);
    short s;
    __builtin_memcpy(&s, &b, 2);
    return s;
}
static __device__ __forceinline__ unsigned fbits(float x) {
    unsigned u;
    __builtin_memcpy(&u, &x, 4);
    return u;
}
static __device__ __forceinline__ float fexp2(float x) {
#if __has_builtin(__builtin_amdgcn_exp2f)
    return __builtin_amdgcn_exp2f(x);
#else
    return exp2f(x);
#endif
}

static __device__ __forceinline__ f32x4 mfma16(bf4 a, bf4 b, f32x4 c) {
#if __has_builtin(__builtin_amdgcn_mfma_f32_16x16x16bf16_1k)
    return __builtin_amdgcn_mfma_f32_16x16x16bf16_1k(a, b, c, 0, 0, 0);
#else
    f32x4 d;
    asm volatile("v_mfma_f32_16x16x16_bf16 %0, %1, %2, %3"
                 : "=&v"(d) : "v"(a), "v"(b), "v"(c));
    return d;
#endif
}

// ---------------- K1: BN partial stats (2-way split) + W->bf16 frags ----
__global__ __launch_bounds__(256) void k_prep(const float* __restrict__ x,
                                              const float* __restrict__ wq,
                                              const float* __restrict__ wk,
                                              const float* __restrict__ wv,
                                              float* __restrict__ ps,
                                              short* __restrict__ wf) {
    int t = threadIdx.x;
    int blk = blockIdx.x;
    if (blk < 256) {
        int c = blk >> 1, half = blk & 1;
        float s1 = 0.f, s2 = 0.f;
        #pragma unroll
        for (int k = 0; k < 4; ++k) {
            int b = half * 4 + k;
            float4 v = ((const float4*)(x + ((size_t)b * CC + c) * NN))[t];
            s1 += v.x + v.y + v.z + v.w;
            s2 += v.x * v.x + v.y * v.y + v.z * v.z + v.w * v.w;
        }
        #pragma unroll
        for (int off = 32; off >= 1; off >>= 1) {
            s1 += __shfl_xor(s1, off);
            s2 += __shfl_xor(s2, off);
        }
        __shared__ float r1[4], r2[4];
        int wid = t >> 6, lane = t & 63;
        if (lane == 0) { r1[wid] = s1; r2[wid] = s2; }
        __syncthreads();
        if (t == 0) {
            ps[c * 4 + half * 2 + 0] = r1[0] + r1[1] + r1[2] + r1[3];
            ps[c * 4 + half * 2 + 1] = r2[0] + r2[1] + r2[2] + r2[3];
        }
    } else {
        // Wf[((p*8+mt)*8+ct)*64 + ln][jj] = W_p[mt*16+li][ct*16+4*hl+jj]
        int s = (blk - 256) * 256 + t;   // 0..12287
        int ln = s & 63, ct = (s >> 6) & 7, mt = (s >> 9) & 7, p = s >> 12;
        int hl = ln >> 4, li = ln & 15;
        const float* w = (p == 0) ? wq : (p == 1) ? wk : wv;
        float4 v = *(const float4*)(w + (size_t)(mt * 16 + li) * CC + ct * 16 + 4 * hl);
        float sc = (p == 0) ? 0.25f * LOG2E : 1.0f;
        bf4 r;
        r[0] = f2bf(v.x * sc); r[1] = f2bf(v.y * sc);
        r[2] = f2bf(v.z * sc); r[3] = f2bf(v.w * sc);
        *(bf4*)&wf[(size_t)s * 4] = r;
    }
}

// ---------------- K2: fused BN+GELU + QKV projection via MFMA -----------
// Wave w owns m-tiles {w, 8+w, 16+w} (one q, one k, one v tile) so the
// V-transpose is wave-private (no block barriers in the epilogue).
__global__ __launch_bounds__(512) void k_proj(const float* __restrict__ x,
                                              const float* __restrict__ ps,
                                              const float* __restrict__ gamma,
                                              const float* __restrict__ beta,
                                              const short* __restrict__ wf,
                                              short* __restrict__ qf,
                                              short* __restrict__ kf,
                                              short* __restrict__ vf) {
    __shared__ float xS[128][20];     // x tile; reused as per-wave vScr later
    __shared__ float ssS[256];
    __shared__ short afS[8][256];
    int it = blockIdx.x, b = blockIdx.y;
    int t = threadIdx.x;
    if (t < 128) {
        int c = t;
        float4 p4 = *(const float4*)(ps + c * 4);
        float s1 = p4.x + p4.z;
        float s2 = p4.y + p4.w;
        float mean = s1 / (float)BHW;
        float var  = s2 / (float)BHW - mean * mean;
        float rstd = rsqrtf(var + 1e-5f);
        float sc = rstd * gamma[c];
        ssS[c]       = sc;
        ssS[128 + c] = beta[c] - mean * sc;
    }
    const float* xb = x + (size_t)b * CC * NN + it * 16;
    {
        int r = t >> 2, cf = t & 3;
        float4 v = *(const float4*)(xb + (size_t)r * NN + cf * 4);
        *(float4*)&xS[r][cf * 4] = v;
    }
    __syncthreads();
    {
        int ct = t >> 6, ln = t & 63;
        int hl_ = ln >> 4, li_ = ln & 15;
        int c0 = ct * 16 + 4 * hl_;
        bf4 r;
        #pragma unroll
        for (int jj = 0; jj < 4; ++jj) {
            int c = c0 + jj;
            float v = xS[c][li_] * ssS[c] + ssS[128 + c];
            v = 0.5f * v * (1.0f + erff(v * 0.70710678f));
            r[jj] = f2bf(v);
        }
        *(bf4*)&afS[ct][ln * 4] = r;
    }
    __syncthreads();

    int wid = t >> 6, lane = t & 63;
    int hl = lane >> 4, li = lane & 15;
    f32x4 acc[3];
    #pragma unroll
    for (int e = 0; e < 3; ++e) acc[e] = (f32x4)0.f;
    #pragma unroll
    for (int ct = 0; ct < 8; ++ct) {
        bf4 af = *(const bf4*)&afS[ct][lane * 4];
        #pragma unroll
        for (int e = 0; e < 3; ++e) {
            int mtp = wid + 8 * e;           // p = e, mt = wid
            bf4 wfr = *(const bf4*)(wf + ((size_t)(mtp * 8 + ct) * 64 + lane) * 4);
            acc[e] = mfma16(wfr, af, acc[e]);
        }
    }
    int bq = b * 8;
    // q/k epilogue: D layout == attention fragment layout, direct store
    #pragma unroll
    for (int e = 0; e < 2; ++e) {
        short* dst = (e == 0) ? qf : kf;
        bf4 r;
        #pragma unroll
        for (int jr = 0; jr < 4; ++jr) r[jr] = f2bf(acc[e][jr]);
        *(bf4*)&dst[(((size_t)(bq + wid) * 64 + it) * 64 + lane) * 4] = r;
    }
    // v epilogue: wave-private 16x16 transpose through LDS (lgkmcnt-ordered)
    {
        float* vScrW = &xS[0][0] + wid * 272;   // [16][17] per wave
        #pragma unroll
        for (int r = 0; r < 4; ++r)
            vScrW[(4 * hl + r) * 17 + li] = acc[2][r];
        bf4 r;
        #pragma unroll
        for (int jj = 0; jj < 4; ++jj)
            r[jj] = f2bf(vScrW[li * 17 + 4 * hl + jj]);
        *(bf4*)&vf[(((size_t)(bq + wid) * 64 + it) * 64 + lane) * 4] = r;
    }
}

// ---------------- K3: one-pass attention, K+V in LDS, constant shift ----
// grid (64, 8), block 512 (8 waves, one 16-query i-tile each).
// P = exp2(s - 32) exactly rescales softmax (per-query-constant shift);
// l accumulated on the MFMA pipe via a ones-fragment.
__global__ __launch_bounds__(512) void k_attn(const short* __restrict__ qf,
                                              const short* __restrict__ kf,
                                              const short* __restrict__ vf,
                                              const float* __restrict__ x,
                                              const float* __restrict__ peh,
                                              const float* __restrict__ pew,
                                              float* __restrict__ out) {
    __shared__ short ldsK[16384];   // 32 KB
    __shared__ short ldsV[16384];   // 32 KB
    __shared__ float phS[64], pwS[64];
    int t = threadIdx.x;
    int bh = blockIdx.x;
    const short* qfh = qf + (size_t)bh * 16384;
    const short* kfh = kf + (size_t)bh * 16384;
    const short* vfh = vf + (size_t)bh * 16384;

    #pragma unroll
    for (int k = 0; k < 4; ++k)
        ((int4*)ldsK)[t + 512 * k] = ((const int4*)kfh)[t + 512 * k];
    #pragma unroll
    for (int k = 0; k < 4; ++k)
        ((int4*)ldsV)[t + 512 * k] = ((const int4*)vfh)[t + 512 * k];
    if (t < 64) {
        phS[t] = (t < 63) ? peh[t] * LOG2E : -1e30f;
        pwS[t] = (t < 63) ? pew[t] * LOG2E : -1e30f;
    }
    __syncthreads();

    int wid = t >> 6, lane = t & 63;
    int li = lane & 15, hl = lane >> 4;
    int it = blockIdx.y * 8 + wid;

    bf4 qfr = *(const bf4*)(qfh + ((size_t)it * 64 + lane) * 4);

    int wi = ((it & 1) << 4) | li;
    float pwm[2][4];
    #pragma unroll
    for (int jp = 0; jp < 2; ++jp)
        #pragma unroll
        for (int r = 0; r < 4; ++r)
            pwm[jp][r] = pwS[wi + 31 - ((jp << 4) + 4 * hl + r)] - MBOUND;

    int hq = it >> 1;
    f32x4 oaccA = (f32x4)0.f, oaccB = (f32x4)0.f;
    f32x4 lacc = (f32x4)0.f;
    short oneb = (short)0x3F80;           // bf16 1.0
    bf4 ones = {oneb, oneb, oneb, oneb};

    bf4 kA[4], kB[4], vA[4], vB[4];
    auto kload = [&](bf4* kb, int ch) {
        #pragma unroll
        for (int jt = 0; jt < 4; ++jt)
            kb[jt] = *(const bf4*)&ldsK[(ch * 4 + jt) * 256 + lane * 4];
    };
    auto vload = [&](bf4* vb, int ch) {
        #pragma unroll
        for (int jt = 0; jt < 4; ++jt)
            vb[jt] = *(const bf4*)&ldsV[(ch * 4 + jt) * 256 + lane * 4];
    };
    auto compute = [&](bf4* kb, bf4* vb, int ch) {
        float ph0 = phS[hq + 31 - 2 * ch];
        float ph1 = phS[hq + 30 - 2 * ch];
        f32x4 s[4];
        #pragma unroll
        for (int jt = 0; jt < 4; ++jt) {
            float ph = (jt < 2) ? ph0 : ph1;
            f32x4 c;
            #pragma unroll
            for (int r = 0; r < 4; ++r) c[r] = pwm[jt & 1][r] + ph;
            s[jt] = mfma16(kb[jt], qfr, c);
        }
        #pragma unroll
        for (int jt = 0; jt < 4; ++jt)
            #pragma unroll
            for (int r = 0; r < 4; ++r)
                s[jt][r] = fexp2(s[jt][r]);
        bf4 pf[4];
        #pragma unroll
        for (int jt = 0; jt < 4; ++jt) {
            unsigned lo = __builtin_amdgcn_perm(fbits(s[jt][1]), fbits(s[jt][0]), 0x07060302u);
            unsigned hi = __builtin_amdgcn_perm(fbits(s[jt][3]), fbits(s[jt][2]), 0x07060302u);
            unsigned pk[2] = {lo, hi};
            __builtin_memcpy(&pf[jt], pk, 8);
        }
        oaccA = mfma16(vb[0], pf[0], oaccA);
        oaccB = mfma16(vb[2], pf[2], oaccB);
        lacc  = mfma16(ones,  pf[0], lacc);
        lacc  = mfma16(ones,  pf[2], lacc);
        oaccA = mfma16(vb[1], pf[1], oaccA);
        oaccB = mfma16(vb[3], pf[3], oaccB);
        lacc  = mfma16(ones,  pf[1], lacc);
        lacc  = mfma16(ones,  pf[3], lacc);
    };

    kload(kA, 0); vload(vA, 0);
    #pragma unroll 1
    for (int ch = 0; ch < 16; ch += 2) {
        kload(kB, ch + 1); vload(vB, ch + 1);
        compute(kA, vA, ch);
        if (ch + 2 < 16) { kload(kA, ch + 2); vload(vA, ch + 2); }
        compute(kB, vB, ch + 1);
    }

    // every lane/reg of lacc already holds the full sum for its query li
    float rl = 1.0f / lacc[0];

    int b = bh >> 3, h = bh & 7;
    size_t base = (size_t)b * (CC * NN) + (size_t)h * KD * NN;
    int i = it * 16 + li;
    #pragma unroll
    for (int r = 0; r < 4; ++r) {
        int d = 4 * hl + r;
        size_t g = base + (size_t)d * NN + i;
        out[g] = x[g] + (oaccA[r] + oaccB[r]) * rl;
    }
}

extern "C" void kernel_launch(void* const* d_in, const int* in_sizes, int n_in,
                              void* d_out, int out_size, void* d_ws, size_t ws_size,
                              hipStream_t stream) {
    const float* x     = (const float*)d_in[0];
    const float* gamma = (const float*)d_in[1];
    const float* beta  = (const float*)d_in[2];
    const float* wq    = (const float*)d_in[3];
    const float* wk    = (const float*)d_in[4];
    const float* wv    = (const float*)d_in[5];
    const float* peh   = (const float*)d_in[6];
    const float* pew   = (const float*)d_in[7];
    float* out = (float*)d_out;
    float* ws  = (float*)d_ws;

    float* ps = ws;                          // 512 f32 partial sums
    short* wf = (short*)(ws + 512);          // 49152 shorts: W bf16 frags
    short* qf = wf + 49152;                  // 1M shorts each (2 MB)
    short* kf = qf + (1 << 20);
    short* vf = kf + (1 << 20);

    k_prep<<<304, 256, 0, stream>>>(x, wq, wk, wv, ps, wf);
    k_proj<<<dim3(64, 8), 512, 0, stream>>>(x, ps, gamma, beta, wf, qf, kf, vf);
    k_attn<<<dim3(64, 8), 512, 0, stream>>>(qf, kf, vf, x, peh, pew, out);
}